// Round 2
// baseline (1515.203 us; speedup 1.0000x reference)
//
#include <hip/hip_runtime.h>

typedef unsigned short u16;
typedef __bf16 bf16x8 __attribute__((ext_vector_type(8)));
typedef float f32x4 __attribute__((ext_vector_type(4)));

__device__ __forceinline__ u16 f2bf(float f) {
  union { float f; unsigned int i; } x; x.f = f;
  unsigned int lsb = (x.i >> 16) & 1u;
  x.i += 0x7fffu + lsb;
  return (u16)(x.i >> 16);
}

// ---------------------------------------------------------------------------
// C[M,N] = (X[M,K] @ W[N,K]^T + bias[N]) * scale ; fp32 accum, bf16 MFMA.
// XF32: X is float32 (converted to bf16 at staging); else X is bf16 (u16).
// YF32: Y written as float32 [M,N]; else bf16 u16 (VT=1 scatters Vt layout).
// Tile 128x128, 4 waves (2x2 of 64x64), BK=32, LDS pad 40 -> 2-way (free).
// ---------------------------------------------------------------------------
template <int VT, int XF32, int YF32>
__global__ __launch_bounds__(256)
void gemm_bt(const void* __restrict__ Xv, const float* __restrict__ W,
             const float* __restrict__ bias, void* __restrict__ Yv,
             int M, int N, int K, float scale) {
  constexpr int TK = 32, LDA = 40;
  __shared__ u16 As[128 * LDA];
  __shared__ u16 Bs[128 * LDA];
  const int tid = threadIdx.x;
  const int wave = tid >> 6, lane = tid & 63;
  const int l15 = lane & 15, quad = lane >> 4;
  const int m0 = blockIdx.y * 128, n0 = blockIdx.x * 128;
  const int wr = (wave >> 1) * 64, wc = (wave & 1) * 64;

  f32x4 zero = {0.f, 0.f, 0.f, 0.f};
  f32x4 acc[4][4];
  for (int i = 0; i < 4; ++i)
    for (int j = 0; j < 4; ++j) acc[i][j] = zero;

  for (int k0 = 0; k0 < K; k0 += TK) {
    __syncthreads();
    // stage X tile (128x32)
    if (XF32) {
      const float* X = (const float*)Xv;
#pragma unroll
      for (int it = 0; it < 4; ++it) {
        int c = tid + 256 * it;          // 1024 chunks of 4 floats
        int row = c >> 3, k4 = (c & 7) * 4;
        float4 v = *(const float4*)(X + (size_t)(m0 + row) * K + k0 + k4);
        u16 p[4] = {f2bf(v.x), f2bf(v.y), f2bf(v.z), f2bf(v.w)};
        *(uint2*)(&As[row * LDA + k4]) = *(const uint2*)p;
      }
    } else {
      const u16* X = (const u16*)Xv;
#pragma unroll
      for (int it = 0; it < 2; ++it) {
        int c = tid + 256 * it;          // 512 chunks of 8 bf16
        int row = c >> 2, kk = (c & 3) * 8;
        *(uint4*)(&As[row * LDA + kk]) =
            *(const uint4*)(X + (size_t)(m0 + row) * K + k0 + kk);
      }
    }
    // stage W tile (128x32), always f32
#pragma unroll
    for (int it = 0; it < 4; ++it) {
      int c = tid + 256 * it;
      int row = c >> 3, k4 = (c & 7) * 4;
      float4 v = *(const float4*)(W + (size_t)(n0 + row) * K + k0 + k4);
      u16 p[4] = {f2bf(v.x), f2bf(v.y), f2bf(v.z), f2bf(v.w)};
      *(uint2*)(&Bs[row * LDA + k4]) = *(const uint2*)p;
    }
    __syncthreads();
    bf16x8 a[4], b[4];
#pragma unroll
    for (int mi = 0; mi < 4; ++mi)
      a[mi] = *(const bf16x8*)(&As[(wr + mi * 16 + l15) * LDA + quad * 8]);
#pragma unroll
    for (int ni = 0; ni < 4; ++ni)
      b[ni] = *(const bf16x8*)(&Bs[(wc + ni * 16 + l15) * LDA + quad * 8]);
#pragma unroll
    for (int mi = 0; mi < 4; ++mi)
#pragma unroll
      for (int ni = 0; ni < 4; ++ni)
        acc[mi][ni] = __builtin_amdgcn_mfma_f32_16x16x32_bf16(
            a[mi], b[ni], acc[mi][ni], 0, 0, 0);
  }

#pragma unroll
  for (int ni = 0; ni < 4; ++ni) {
    int col = n0 + wc + ni * 16 + l15;
    float bv = bias[col];
#pragma unroll
    for (int mi = 0; mi < 4; ++mi)
#pragma unroll
      for (int r = 0; r < 4; ++r) {
        int row = m0 + wr + mi * 16 + quad * 4 + r;
        float v = (acc[mi][ni][r] + bv) * scale;
        if (YF32) {
          ((float*)Yv)[(size_t)row * N + col] = v;
        } else {
          u16 u = f2bf(v);
          if (VT) {
            // row = b*4096 + n ; col = h*64 + d  ->  Vt[(b*8+h)*64+d][n]
            int b_ = row >> 12, n_ = row & 4095;
            int h_ = col >> 6, d_ = col & 63;
            ((u16*)Yv)[((size_t)((b_ * 8 + h_) * 64 + d_) << 12) + n_] = u;
          } else {
            ((u16*)Yv)[(size_t)row * N + col] = u;
          }
        }
      }
  }
}

// ---------------------------------------------------------------------------
// Fused attention: one block = one (b,h) x 128 query rows. Two passes over K:
// pass 1 computes per-row (m,l); pass 2 recomputes S, writes normalized A
// (f32, direct from registers) and accumulates ctx = A @ V via MFMA.
// Q pre-scaled by 1/sqrt(Dh). Scratch Q/K/Vt/ctx are bf16.
// ---------------------------------------------------------------------------
__global__ __launch_bounds__(256)
void attn_fused(const u16* __restrict__ Q, const u16* __restrict__ Km,
                const u16* __restrict__ Vt, u16* __restrict__ ctx,
                float* __restrict__ attnw) {
  constexpr int LD = 72;  // 144B row stride -> 2-way banks (free)
  __shared__ u16 Qs[128 * LD];
  __shared__ u16 Ks[64 * LD];
  __shared__ u16 Vs[64 * LD];
  __shared__ u16 As[128 * LD];
  const int tid = threadIdx.x;
  const int wave = tid >> 6, lane = tid & 63;
  const int l15 = lane & 15, quad = lane >> 4;
  const int bh = blockIdx.y, b = bh >> 3, h = bh & 7;
  const int q0 = blockIdx.x * 128;
  const int wrow = wave * 32;

#pragma unroll
  for (int it = 0; it < 4; ++it) {  // stage Q tile 128x64 (bf16)
    int c = tid + 256 * it;
    int row = c >> 3, c8 = (c & 7) * 8;
    *(uint4*)(&Qs[row * LD + c8]) =
        *(const uint4*)(Q + (size_t)(b * 4096 + q0 + row) * 512 + h * 64 + c8);
  }
  float m_run[2][4], l_run[2][4];
#pragma unroll
  for (int mi = 0; mi < 2; ++mi)
    for (int r = 0; r < 4; ++r) { m_run[mi][r] = -__builtin_inff(); l_run[mi][r] = 0.f; }
  __syncthreads();

  f32x4 zero = {0.f, 0.f, 0.f, 0.f};

  // ---- pass 1: row max + sumexp ----
  for (int ki = 0; ki < 64; ++ki) {
#pragma unroll
    for (int it = 0; it < 2; ++it) {
      int c = tid + 256 * it;
      int row = c >> 3, c8 = (c & 7) * 8;
      *(uint4*)(&Ks[row * LD + c8]) = *(const uint4*)(
          Km + (size_t)(b * 4096 + ki * 64 + row) * 512 + h * 64 + c8);
    }
    __syncthreads();
    f32x4 s[2][4];
    for (int mi = 0; mi < 2; ++mi)
      for (int ni = 0; ni < 4; ++ni) s[mi][ni] = zero;
#pragma unroll
    for (int kk = 0; kk < 2; ++kk) {
      bf16x8 a[2], bb[4];
      for (int mi = 0; mi < 2; ++mi)
        a[mi] = *(const bf16x8*)(&Qs[(wrow + mi * 16 + l15) * LD + kk * 32 + quad * 8]);
      for (int ni = 0; ni < 4; ++ni)
        bb[ni] = *(const bf16x8*)(&Ks[(ni * 16 + l15) * LD + kk * 32 + quad * 8]);
      for (int mi = 0; mi < 2; ++mi)
        for (int ni = 0; ni < 4; ++ni)
          s[mi][ni] = __builtin_amdgcn_mfma_f32_16x16x32_bf16(
              a[mi], bb[ni], s[mi][ni], 0, 0, 0);
    }
#pragma unroll
    for (int mi = 0; mi < 2; ++mi)
#pragma unroll
      for (int r = 0; r < 4; ++r) {
        float mc = fmaxf(fmaxf(s[mi][0][r], s[mi][1][r]),
                         fmaxf(s[mi][2][r], s[mi][3][r]));
#pragma unroll
        for (int off = 1; off < 16; off <<= 1) mc = fmaxf(mc, __shfl_xor(mc, off, 16));
        float el = __expf(s[mi][0][r] - mc) + __expf(s[mi][1][r] - mc) +
                   __expf(s[mi][2][r] - mc) + __expf(s[mi][3][r] - mc);
#pragma unroll
        for (int off = 1; off < 16; off <<= 1) el += __shfl_xor(el, off, 16);
        float mn = fmaxf(m_run[mi][r], mc);
        l_run[mi][r] = l_run[mi][r] * __expf(m_run[mi][r] - mn) + el * __expf(mc - mn);
        m_run[mi][r] = mn;
      }
    __syncthreads();
  }

  float inv_l[2][4];
  for (int mi = 0; mi < 2; ++mi)
    for (int r = 0; r < 4; ++r) inv_l[mi][r] = 1.0f / l_run[mi][r];

  f32x4 o[2][4];
  for (int mi = 0; mi < 2; ++mi)
    for (int ni = 0; ni < 4; ++ni) o[mi][ni] = zero;

  const size_t awbase = ((size_t)bh << 24);

  // ---- pass 2: recompute S, write normalized A (f32), accumulate ctx ----
  for (int ki = 0; ki < 64; ++ki) {
#pragma unroll
    for (int it = 0; it < 2; ++it) {
      int c = tid + 256 * it;
      int row = c >> 3, c8 = (c & 7) * 8;
      *(uint4*)(&Ks[row * LD + c8]) = *(const uint4*)(
          Km + (size_t)(b * 4096 + ki * 64 + row) * 512 + h * 64 + c8);
      *(uint4*)(&Vs[row * LD + c8]) =
          *(const uint4*)(Vt + ((size_t)(bh * 64 + row) << 12) + ki * 64 + c8);
    }
    __syncthreads();
    f32x4 s[2][4];
    for (int mi = 0; mi < 2; ++mi)
      for (int ni = 0; ni < 4; ++ni) s[mi][ni] = zero;
#pragma unroll
    for (int kk = 0; kk < 2; ++kk) {
      bf16x8 a[2], bb[4];
      for (int mi = 0; mi < 2; ++mi)
        a[mi] = *(const bf16x8*)(&Qs[(wrow + mi * 16 + l15) * LD + kk * 32 + quad * 8]);
      for (int ni = 0; ni < 4; ++ni)
        bb[ni] = *(const bf16x8*)(&Ks[(ni * 16 + l15) * LD + kk * 32 + quad * 8]);
      for (int mi = 0; mi < 2; ++mi)
        for (int ni = 0; ni < 4; ++ni)
          s[mi][ni] = __builtin_amdgcn_mfma_f32_16x16x32_bf16(
              a[mi], bb[ni], s[mi][ni], 0, 0, 0);
    }
    // normalized A: bf16 -> LDS (for PV MFMA), f32 -> global (output 1)
#pragma unroll
    for (int mi = 0; mi < 2; ++mi)
#pragma unroll
      for (int ni = 0; ni < 4; ++ni)
#pragma unroll
        for (int r = 0; r < 4; ++r) {
          float av = __expf(s[mi][ni][r] - m_run[mi][r]) * inv_l[mi][r];
          int arow = wrow + mi * 16 + quad * 4 + r;
          As[arow * LD + ni * 16 + l15] = f2bf(av);
          attnw[awbase + (size_t)(q0 + arow) * 4096 + ki * 64 + ni * 16 + l15] = av;
        }
    __syncthreads();
    // ctx += A @ V
#pragma unroll
    for (int kk = 0; kk < 2; ++kk) {
      bf16x8 a[2], bb[4];
      for (int mi = 0; mi < 2; ++mi)
        a[mi] = *(const bf16x8*)(&As[(wrow + mi * 16 + l15) * LD + kk * 32 + quad * 8]);
      for (int ni = 0; ni < 4; ++ni)
        bb[ni] = *(const bf16x8*)(&Vs[(ni * 16 + l15) * LD + kk * 32 + quad * 8]);
      for (int mi = 0; mi < 2; ++mi)
        for (int ni = 0; ni < 4; ++ni)
          o[mi][ni] = __builtin_amdgcn_mfma_f32_16x16x32_bf16(
              a[mi], bb[ni], o[mi][ni], 0, 0, 0);
    }
    __syncthreads();
  }

  // ctx epilogue (bf16 scratch)
#pragma unroll
  for (int mi = 0; mi < 2; ++mi)
    for (int ni = 0; ni < 4; ++ni)
      for (int r = 0; r < 4; ++r) {
        int row = wrow + mi * 16 + quad * 4 + r;
        int d = ni * 16 + l15;
        ctx[(size_t)(b * 4096 + q0 + row) * 512 + h * 64 + d] = f2bf(o[mi][ni][r]);
      }
}

extern "C" void kernel_launch(void* const* d_in, const int* in_sizes, int n_in,
                              void* d_out, int out_size, void* d_ws, size_t ws_size,
                              hipStream_t stream) {
  const float* query = (const float*)d_in[0];
  const float* key   = (const float*)d_in[1];
  const float* value = (const float*)d_in[2];
  const float* Wq = (const float*)d_in[3];
  const float* bq = (const float*)d_in[4];
  const float* Wk = (const float*)d_in[5];
  const float* bk = (const float*)d_in[6];
  const float* Wv = (const float*)d_in[7];
  const float* bv = (const float*)d_in[8];
  const float* Wo = (const float*)d_in[9];
  const float* bo = (const float*)d_in[10];

  float* out  = (float*)d_out;
  float* attn = out + (size_t)2 * 4096 * 512;     // f32 outputs, concatenated

  u16* q   = (u16*)d_ws;                          // [8192][512] bf16, pre-scaled
  u16* k   = q  + (size_t)8192 * 512;             // [8192][512]
  u16* vt  = k  + (size_t)8192 * 512;             // [16][64][4096]
  u16* ctx = vt + (size_t)8192 * 512;             // [8192][512]

  dim3 gg(4, 64), bb(256, 1, 1);
  gemm_bt<0, 1, 0><<<gg, bb, 0, stream>>>(query, Wq, bq, q, 8192, 512, 512, 0.125f);
  gemm_bt<0, 1, 0><<<gg, bb, 0, stream>>>(key,   Wk, bk, k, 8192, 512, 512, 1.0f);
  gemm_bt<1, 1, 0><<<gg, bb, 0, stream>>>(value, Wv, bv, vt, 8192, 512, 512, 1.0f);
  attn_fused<<<dim3(32, 16, 1), bb, 0, stream>>>(q, k, vt, ctx, attn);
  gemm_bt<0, 0, 1><<<gg, bb, 0, stream>>>(ctx, Wo, bo, out, 8192, 512, 512, 1.0f);
}